// Round 1
// baseline (189.524 us; speedup 1.0000x reference)
//
#include <hip/hip_runtime.h>

// Problem constants (from reference setup_inputs)
constexpr int Bc = 8;
constexpr int Nc = 300;
constexpr int Cc = 256;
constexpr int Pc = 32;

typedef float f32x4 __attribute__((ext_vector_type(4)));

// All four levels staged to LDS (floats): f0 10000, f1 2500, f2 625, f3 169
constexpr int F0_OFF = 0;
constexpr int S1_OFF = 10000;
constexpr int S2_OFF = 12500;
constexpr int S3_OFF = 13125;
constexpr int STAGE2_FLOATS = 13296;   // 53184 B, 16B multiple -> 3 blocks/CU

// ---- async global->LDS DMA ----
__device__ __forceinline__ void gl_lds16(const void* g, void* l) {
    __builtin_amdgcn_global_load_lds(
        (const __attribute__((address_space(1))) void*)g,
        (__attribute__((address_space(3))) void*)l, 16, 0, 0);
}
__device__ __forceinline__ void gl_lds4(const void* g, void* l) {
    __builtin_amdgcn_global_load_lds(
        (const __attribute__((address_space(1))) void*)g,
        (__attribute__((address_space(3))) void*)l, 4, 0, 0);
}

// ---------------------------------------------------------------------------
// Kernel 1: per-query params, one wave per query.
// params[q*8 + {0:sx, 1:sy, 2..5: zw[l], 6..7: unused}]
// ---------------------------------------------------------------------------
__global__ __launch_bounds__(256) void params_kernel(
    const float* __restrict__ qpos, const float* __restrict__ qcont,
    const float* __restrict__ Woff, const float* __restrict__ boff,
    const float* __restrict__ sigma, float* __restrict__ params)
{
    const int w = threadIdx.x >> 6;
    const int lane = threadIdx.x & 63;
    const int q = blockIdx.x * 4 + w;          // 600*4 = 2400 queries

    f32x4 qc = *(const f32x4*)&qcont[(size_t)q * Cc + lane * 4];
    float p0 = 0.f, p1 = 0.f, p2 = 0.f;
#pragma unroll
    for (int j = 0; j < 4; ++j) {
        const float* wr = &Woff[(lane * 4 + j) * 3];
        p0 += qc[j] * wr[0];
        p1 += qc[j] * wr[1];
        p2 += qc[j] * wr[2];
    }
#pragma unroll
    for (int off = 32; off > 0; off >>= 1) {
        p0 += __shfl_down(p0, off, 64);
        p1 += __shfl_down(p1, off, 64);
        p2 += __shfl_down(p2, off, 64);
    }
    if (lane == 0) {
        float dx = p0 + boff[0];
        float dy = p1 + boff[1];
        float dz = p2 + boff[2];
        float x = qpos[q * 4 + 0];
        float y = qpos[q * 4 + 1];
        float z = qpos[q * 4 + 2];
        float r = qpos[q * 4 + 3];
        float sx = x + dx * exp2f(z - r);
        float sy = y + dy * exp2f(z + r);
        float sz = z + dz;
        float sg = sigma[0];
        float inv = 1.0f / (2.0f * sg * sg);
        float e[4];
        float s = 0.f;
#pragma unroll
        for (int l = 0; l < 4; ++l) {
            float d = sz - (float)l;
            float wgt = __expf(-d * d * inv);  // gaussian weight in (0,1]
            e[l] = __expf(wgt);                // softmax numerator of that weight
            s += e[l];
        }
        float rs = 1.0f / s;
        params[q * 8 + 0] = sx;
        params[q * 8 + 1] = sy;
#pragma unroll
        for (int l = 0; l < 4; ++l) params[q * 8 + 2 + l] = e[l] * rs;
    }
}

// bilinear coords, border padding, align_corners=False
struct BilinW { int i00, i01, i10, i11; float wx, wy; };
__device__ __forceinline__ BilinW bilin(int W, float sx, float sy) {
    float px = fminf(fmaxf(sx - 0.5f, 0.f), (float)(W - 1));
    float py = fminf(fmaxf(sy - 0.5f, 0.f), (float)(W - 1));
    float x0f = floorf(px);
    float y0f = floorf(py);
    int x0 = (int)x0f;
    int y0 = (int)y0f;
    int x1 = min(x0 + 1, W - 1);
    int y1 = min(y0 + 1, W - 1);
    BilinW r;
    r.wx = px - x0f;
    r.wy = py - y0f;
    r.i00 = y0 * W + x0; r.i01 = y0 * W + x1;
    r.i10 = y1 * W + x0; r.i11 = y1 * W + x1;
    return r;
}
__device__ __forceinline__ float blend(float v00, float v01, float v10, float v11,
                                       float wx, float wy) {
    float top = v00 + wx * (v01 - v00);
    float bot = v10 + wx * (v11 - v10);
    return top + wy * (bot - top);
}

// ---------------------------------------------------------------------------
// Kernel 2 (R9): one block per (b,c) slice, grid 2048. ALL four levels
// staged to LDS via streamed async DMA (53.2 KB -> 3 blocks/CU, 12 waves/CU).
// Converts the former scattered level-0 HBM gathers (~60-75 MB of random
// 64B line fetches) into an 82 MB sequential stream at full DRAM efficiency;
// all 16 taps/query become LDS reads.
// outT[(b*Cc + c)*Nc + n]  <- coalesced (thread index = n)
// ---------------------------------------------------------------------------
__global__ __launch_bounds__(256, 3) void sample_kernel(
    const float* __restrict__ f0, const float* __restrict__ f1,
    const float* __restrict__ f2, const float* __restrict__ f3,
    const float* __restrict__ params, float* __restrict__ outT)
{
    __shared__ __align__(16) float sl[STAGE2_FLOATS];
    const int bc = blockIdx.x;           // b*Cc + c
    const int t = threadIdx.x;
    const int b = bc >> 8;
    const int wave = t >> 6;
    const int lane = t & 63;

    // ---- per-thread query params (issued early; needed after barrier) ----
    const int q0 = b * Nc + t;
    const bool has2 = (t < Nc - 256);    // t < 44
    f32x4 pa0 = *(const f32x4*)&params[(size_t)q0 * 8];      // {sx, sy, zw0, zw1}
    f32x4 pb0 = *(const f32x4*)&params[(size_t)q0 * 8 + 4];  // {zw2, zw3, -, -}
    f32x4 pa1 = {0, 0, 0, 0}, pb1 = {0, 0, 0, 0};
    if (has2) {
        pa1 = *(const f32x4*)&params[(size_t)(q0 + 256) * 8];
        pb1 = *(const f32x4*)&params[(size_t)(q0 + 256) * 8 + 4];
    }
    const float sx0 = pa0.x, sy0 = pa0.y;
    const float sx1 = pa1.x, sy1 = pa1.y;

    // ---- async-stage all levels (fire-and-forget; drained at barrier) ----
    {
        // level 0: 40000 B, 16B-aligned. 39 x 1024 B + 64 B tail (4 lanes).
        const char* g0 = (const char*)(f0 + (size_t)bc * 10000);
        char* l0 = (char*)&sl[F0_OFF];
        for (int i = wave; i < 39; i += 4)
            gl_lds16(g0 + i * 1024 + lane * 16, l0 + i * 1024);
        if (wave == 0 && lane < 4)
            gl_lds16(g0 + 39 * 1024 + lane * 16, l0 + 39 * 1024);
        // level 1: 10000 B, 16B-aligned. 9 x 1024 B + 784 B tail (49 lanes).
        const char* g1 = (const char*)(f1 + (size_t)bc * 2500);
        char* l1 = (char*)&sl[S1_OFF];
        for (int i = wave; i < 9; i += 4)
            gl_lds16(g1 + i * 1024 + lane * 16, l1 + i * 1024);
        if (wave == 1 && lane < 49)
            gl_lds16(g1 + 9 * 1024 + lane * 16, l1 + 9 * 1024);
        // level 2: 2500 B, 4B-aligned -> width-4. 9 x 256 B + 196 B tail.
        const char* g2 = (const char*)(f2 + (size_t)bc * 625);
        char* l2 = (char*)&sl[S2_OFF];
        for (int i = wave; i < 9; i += 4)
            gl_lds4(g2 + i * 256 + lane * 4, l2 + i * 256);
        if (wave == 2 && lane < 49)
            gl_lds4(g2 + 9 * 256 + lane * 4, l2 + 9 * 256);
        // level 3: 676 B, 4B-aligned -> width-4. 2 x 256 B + 164 B tail.
        const char* g3 = (const char*)(f3 + (size_t)bc * 169);
        char* l3 = (char*)&sl[S3_OFF];
        for (int i = wave; i < 2; i += 4)
            gl_lds4(g3 + i * 256 + lane * 4, l3 + i * 256);
        if (wave == 3 && lane < 41)
            gl_lds4(g3 + 2 * 256 + lane * 4, l3 + 2 * 256);
    }

    __syncthreads();   // drains DMA

    // ---- combine: all four levels from LDS ----
    {
        BilinW w0 = bilin(100, sx0, sy0);
        BilinW w1 = bilin(50, sx0, sy0);
        BilinW w2 = bilin(25, sx0, sy0);
        BilinW w3 = bilin(13, sx0, sy0);
        float acc = pa0.z * blend(sl[F0_OFF + w0.i00], sl[F0_OFF + w0.i01],
                                  sl[F0_OFF + w0.i10], sl[F0_OFF + w0.i11], w0.wx, w0.wy)
                  + pa0.w * blend(sl[S1_OFF + w1.i00], sl[S1_OFF + w1.i01],
                                  sl[S1_OFF + w1.i10], sl[S1_OFF + w1.i11], w1.wx, w1.wy)
                  + pb0.x * blend(sl[S2_OFF + w2.i00], sl[S2_OFF + w2.i01],
                                  sl[S2_OFF + w2.i10], sl[S2_OFF + w2.i11], w2.wx, w2.wy)
                  + pb0.y * blend(sl[S3_OFF + w3.i00], sl[S3_OFF + w3.i01],
                                  sl[S3_OFF + w3.i10], sl[S3_OFF + w3.i11], w3.wx, w3.wy);
        outT[(size_t)bc * Nc + t] = acc;
    }
    if (has2) {
        BilinW w0 = bilin(100, sx1, sy1);
        BilinW w1 = bilin(50, sx1, sy1);
        BilinW w2 = bilin(25, sx1, sy1);
        BilinW w3 = bilin(13, sx1, sy1);
        float acc = pa1.z * blend(sl[F0_OFF + w0.i00], sl[F0_OFF + w0.i01],
                                  sl[F0_OFF + w0.i10], sl[F0_OFF + w0.i11], w0.wx, w0.wy)
                  + pa1.w * blend(sl[S1_OFF + w1.i00], sl[S1_OFF + w1.i01],
                                  sl[S1_OFF + w1.i10], sl[S1_OFF + w1.i11], w1.wx, w1.wy)
                  + pb1.x * blend(sl[S2_OFF + w2.i00], sl[S2_OFF + w2.i01],
                                  sl[S2_OFF + w2.i10], sl[S2_OFF + w2.i11], w2.wx, w2.wy)
                  + pb1.y * blend(sl[S3_OFF + w3.i00], sl[S3_OFF + w3.i01],
                                  sl[S3_OFF + w3.i10], sl[S3_OFF + w3.i11], w3.wx, w3.wy);
        outT[(size_t)bc * Nc + t + 256] = acc;
    }
}

// ---------------------------------------------------------------------------
// Kernel 3: one block per FOUR queries (300 % 4 == 0 so all 4 share b).
// float4 outT reads (4x fewer L2/L3 line fetches than per-query dwords),
// broadcast over P with NT float4 stores.
// ---------------------------------------------------------------------------
__global__ __launch_bounds__(256) void broadcast_kernel(
    const float* __restrict__ outT, float* __restrict__ out)
{
    __shared__ float sval[4][Cc];
    const int q0 = blockIdx.x * 4;       // 600 blocks
    const int b = q0 / Nc;
    const int n0 = q0 - b * Nc;          // multiple of 4
    const int c = threadIdx.x;
    // ((b*256+c)*300 + n0) is a multiple of 4 -> 16B-aligned float4
    f32x4 v = *(const f32x4*)&outT[((size_t)(b * Cc + c)) * Nc + n0];
#pragma unroll
    for (int j = 0; j < 4; ++j) sval[j][c] = v[j];
    __syncthreads();

    const int wave = threadIdx.x >> 6;
    const int c4 = (threadIdx.x & 63) * 4;
#pragma unroll
    for (int j = 0; j < 4; ++j) {
        f32x4 val = *(const f32x4*)&sval[j][c4];
        float* obase = out + (size_t)(q0 + j) * (Pc * Cc) + c4;
#pragma unroll
        for (int p = wave; p < Pc; p += 4) {
            __builtin_nontemporal_store(val, (f32x4*)(obase + p * Cc));
        }
    }
}

// ---------------------------------------------------------------------------
// Fallback: proven single-kernel path (if ws too small). Not expected to run.
// ---------------------------------------------------------------------------
__global__ __launch_bounds__(256) void sampling3d_fallback(
    const float* __restrict__ f0, const float* __restrict__ f1,
    const float* __restrict__ f2, const float* __restrict__ f3,
    const float* __restrict__ qpos, const float* __restrict__ qcont,
    const float* __restrict__ Woff, const float* __restrict__ boff,
    const float* __restrict__ sigma, float* __restrict__ out)
{
    const int q = blockIdx.x;
    const int b = q / Nc;
    const int c = threadIdx.x;
    float qc = qcont[q * Cc + c];
    float p0 = qc * Woff[c * 3 + 0];
    float p1 = qc * Woff[c * 3 + 1];
    float p2 = qc * Woff[c * 3 + 2];
#pragma unroll
    for (int off = 32; off > 0; off >>= 1) {
        p0 += __shfl_down(p0, off, 64);
        p1 += __shfl_down(p1, off, 64);
        p2 += __shfl_down(p2, off, 64);
    }
    __shared__ float red[4][3];
    __shared__ float par[8];
    __shared__ float accs[Cc];
    const int wave = threadIdx.x >> 6;
    if ((threadIdx.x & 63) == 0) { red[wave][0] = p0; red[wave][1] = p1; red[wave][2] = p2; }
    __syncthreads();
    if (threadIdx.x == 0) {
        float dx = red[0][0] + red[1][0] + red[2][0] + red[3][0] + boff[0];
        float dy = red[0][1] + red[1][1] + red[2][1] + red[3][1] + boff[1];
        float dz = red[0][2] + red[1][2] + red[2][2] + red[3][2] + boff[2];
        float x = qpos[q * 4 + 0], y = qpos[q * 4 + 1];
        float z = qpos[q * 4 + 2], r = qpos[q * 4 + 3];
        float sx = x + dx * exp2f(z - r);
        float sy = y + dy * exp2f(z + r);
        float sz = z + dz;
        float sg = sigma[0];
        float inv = 1.0f / (2.0f * sg * sg);
        float e[4]; float s = 0.f;
#pragma unroll
        for (int l = 0; l < 4; ++l) {
            float d = sz - (float)l;
            float w = __expf(-d * d * inv);
            e[l] = __expf(w);
            s += e[l];
        }
        float rs = 1.0f / s;
        par[0] = sx; par[1] = sy;
#pragma unroll
        for (int l = 0; l < 4; ++l) par[2 + l] = e[l] * rs;
    }
    __syncthreads();
    const float sx = par[0];
    const float sy = par[1];
    const float* const fs[4] = {f0, f1, f2, f3};
    const int HWs[4] = {100, 50, 25, 13};
    float acc = 0.f;
#pragma unroll
    for (int l = 0; l < 4; ++l) {
        const int W = HWs[l];
        float px = fminf(fmaxf(sx - 0.5f, 0.f), (float)(W - 1));
        float py = fminf(fmaxf(sy - 0.5f, 0.f), (float)(W - 1));
        float x0f = floorf(px), y0f = floorf(py);
        float wx = px - x0f, wy = py - y0f;
        int x0 = (int)x0f, y0 = (int)y0f;
        int x1 = min(x0 + 1, W - 1), y1 = min(y0 + 1, W - 1);
        const float* base = fs[l] + (size_t)((b * Cc + c) * W) * W;
        float v00 = base[y0 * W + x0];
        float v01 = base[y0 * W + x1];
        float v10 = base[y1 * W + x0];
        float v11 = base[y1 * W + x1];
        float top = v00 + wx * (v01 - v00);
        float bot = v10 + wx * (v11 - v10);
        acc += par[2 + l] * (top + wy * (bot - top));
    }
    accs[c] = acc;
    __syncthreads();
    const int c4 = (threadIdx.x & 63) * 4;
    f32x4 val = *(const f32x4*)&accs[c4];
    float* obase = out + (size_t)q * (Pc * Cc) + c4;
#pragma unroll
    for (int p = wave; p < Pc; p += 4) {
        __builtin_nontemporal_store(val, (f32x4*)(obase + p * Cc));
    }
}

extern "C" void kernel_launch(void* const* d_in, const int* in_sizes, int n_in,
                              void* d_out, int out_size, void* d_ws, size_t ws_size,
                              hipStream_t stream) {
    const float* f0    = (const float*)d_in[0];
    const float* f1    = (const float*)d_in[1];
    const float* f2    = (const float*)d_in[2];
    const float* f3    = (const float*)d_in[3];
    const float* qpos  = (const float*)d_in[4];
    const float* qcont = (const float*)d_in[5];
    const float* Woff  = (const float*)d_in[6];
    const float* boff  = (const float*)d_in[7];
    const float* sigma = (const float*)d_in[8];
    float* out = (float*)d_out;

    const size_t params_bytes = (size_t)Bc * Nc * 8 * sizeof(float);      // 76.8 KB
    const size_t outT_bytes   = (size_t)Bc * Cc * Nc * sizeof(float);     // 2.46 MB

    if (ws_size >= params_bytes + outT_bytes) {
        float* params = (float*)d_ws;
        float* outT   = (float*)((char*)d_ws + params_bytes);
        params_kernel<<<Bc * Nc / 4, 256, 0, stream>>>(qpos, qcont, Woff, boff, sigma, params);
        sample_kernel<<<Bc * Cc, 256, 0, stream>>>(f0, f1, f2, f3, params, outT);
        broadcast_kernel<<<Bc * Nc / 4, 256, 0, stream>>>(outT, out);
    } else {
        sampling3d_fallback<<<Bc * Nc, 256, 0, stream>>>(
            f0, f1, f2, f3, qpos, qcont, Woff, boff, sigma, out);
    }
}